// Round 10
// baseline (319.644 us; speedup 1.0000x reference)
//
#include <hip/hip_runtime.h>
#include <cstdint>
#include <cstddef>

#define D_MODEL 1024
#define NHEADS  16
#define DK      64
#define SEQ     2048
#define NBATCH  2

#define NEG_BIG (-1e30f)

typedef __attribute__((ext_vector_type(8))) short bf16x8;
typedef __attribute__((ext_vector_type(4))) short bf16x4;
typedef __attribute__((ext_vector_type(4))) float f32x4;

// Host pass: amdgcn builtins unavailable -> guard on __AMDGCN__.
__device__ inline f32x4 mfma16x16x16(bf16x4 a, bf16x4 b, f32x4 c) {
#if defined(__AMDGCN__)
# if __has_builtin(__builtin_amdgcn_mfma_f32_16x16x16_bf16)
  return __builtin_amdgcn_mfma_f32_16x16x16_bf16(a, b, c, 0, 0, 0);
# else
  return __builtin_amdgcn_mfma_f32_16x16x16bf16_1k(a, b, c, 0, 0, 0);
# endif
#else
  (void)a; (void)b;
  return c;
#endif
}

__device__ inline void gll16(const unsigned short* g, unsigned short* l) {
#if defined(__AMDGCN__)
  __builtin_amdgcn_global_load_lds(
      (const __attribute__((address_space(1))) void*)g,
      (__attribute__((address_space(3))) void*)l, 16, 0, 0);
#else
  (void)g; (void)l;
#endif
}

__device__ inline unsigned short f2bf(float f) {
  unsigned int u = __float_as_uint(f);
  u += 0x7fffu + ((u >> 16) & 1u);   // round-to-nearest-even
  return (unsigned short)(u >> 16);
}

// ---------------------------------------------------------------------------
// Kernel 0: dtype sniffer (fp32 vs bf16 input buffers). flag=1 -> fp32.
// ---------------------------------------------------------------------------
__global__ __launch_bounds__(256) void sniff_kernel(
    const unsigned short* __restrict__ x, unsigned int* __restrict__ flag) {
  __shared__ int red[256];
  int cnt = 0;
  for (int j = threadIdx.x; j < 32768; j += 256) {
    const unsigned int u = x[2 * j];
    const unsigned int e = (u >> 7) & 0xFFu;
    cnt += (e >= 0x84u) ? 1 : 0;
  }
  red[threadIdx.x] = cnt;
  __syncthreads();
  for (int s = 128; s > 0; s >>= 1) {
    if (threadIdx.x < s) red[threadIdx.x] += red[threadIdx.x + s];
    __syncthreads();
  }
  if (threadIdx.x == 0) *flag = (red[0] > 100) ? 1u : 0u;
}

// ---------------------------------------------------------------------------
// Kernel 0b: canonicalize to bf16. n8 = element_count / 8.
// ---------------------------------------------------------------------------
__global__ __launch_bounds__(256) void cvt_kernel(
    const void* __restrict__ src, unsigned short* __restrict__ dst, int n8,
    const unsigned int* __restrict__ flag) {
  const int i = blockIdx.x * 256 + threadIdx.x;
  if (i >= n8) return;
  if (*flag != 0u) {
    const float4* s = (const float4*)src;
    float4 a = s[2 * i], b = s[2 * i + 1];
    uint4 r;
    r.x = (unsigned)f2bf(a.x) | ((unsigned)f2bf(a.y) << 16);
    r.y = (unsigned)f2bf(a.z) | ((unsigned)f2bf(a.w) << 16);
    r.z = (unsigned)f2bf(b.x) | ((unsigned)f2bf(b.y) << 16);
    r.w = (unsigned)f2bf(b.z) | ((unsigned)f2bf(b.w) << 16);
    ((uint4*)dst)[i] = r;
  } else {
    ((uint4*)dst)[i] = ((const uint4*)src)[i];
  }
}

// ---------------------------------------------------------------------------
// 128x64 tile GEMM mainloop, transposed-C, async staging.
// ---------------------------------------------------------------------------
__device__ inline void gemm_bt_64T(const unsigned short* __restrict__ A,
                                   const unsigned short* __restrict__ W,
                                   int m0, int n0,
                                   unsigned short* As, unsigned short* Bs,
                                   f32x4 acc[2][4]) {
  const int t    = threadIdx.x;
  const int lane = t & 63;
  const int w    = t >> 6;
  const int wm   = (w >> 1) * 64;   // token offset
  const int wn   = (w & 1) * 32;    // feature offset
  const int frow = lane & 15;
  const int fk   = (lane >> 4) * 8;

  for (int ft = 0; ft < 2; ++ft)
    for (int tt = 0; tt < 4; ++tt)
      acc[ft][tt] = (f32x4){0.f, 0.f, 0.f, 0.f};

  const int r0  = t >> 2;
  const int kc0 = (t & 3) << 3;

  for (int k0 = 0; k0 < 1024; k0 += 32) {
    __syncthreads();
    gll16(A + (size_t)(m0 + r0) * 1024 + k0 + kc0,      As + (size_t)t * 8);
    gll16(A + (size_t)(m0 + r0 + 64) * 1024 + k0 + kc0, As + (size_t)(t + 256) * 8);
    gll16(W + (size_t)(n0 + r0) * 1024 + k0 + kc0,      Bs + (size_t)t * 8);
    __syncthreads();

    bf16x8 xf[4], wf[2];
#pragma unroll
    for (int tt = 0; tt < 4; ++tt)
      xf[tt] = *(const bf16x8*)(As + (wm + tt * 16 + frow) * 32 + fk);
#pragma unroll
    for (int ft = 0; ft < 2; ++ft)
      wf[ft] = *(const bf16x8*)(Bs + (wn + ft * 16 + frow) * 32 + fk);
#pragma unroll
    for (int ft = 0; ft < 2; ++ft)
#pragma unroll
      for (int tt = 0; tt < 4; ++tt)
        acc[ft][tt] = __builtin_amdgcn_mfma_f32_16x16x32_bf16(wf[ft], xf[tt],
                                                              acc[ft][tt], 0, 0, 0);
  }
}

// ---------------------------------------------------------------------------
// Kernel 1: QKV projection + fused RoPE (in-register pairs), packed stores.
// ---------------------------------------------------------------------------
__global__ __launch_bounds__(256) void qkv_rope_kernel(
    const unsigned short* __restrict__ x,
    const unsigned short* __restrict__ wqkv,
    unsigned short* __restrict__ Qw, unsigned short* __restrict__ Kw,
    unsigned short* __restrict__ Vw) {
  __shared__ __align__(16) unsigned short As[128 * 32];
  __shared__ __align__(16) unsigned short Bs[64 * 32];
  f32x4 acc[2][4];
  const int m0 = blockIdx.x * 128;
  const int n0 = blockIdx.y * 64;
  gemm_bt_64T(x, wqkv, m0, n0, As, Bs, acc);

  const int t = threadIdx.x, lane = t & 63, w = t >> 6;
  const int wm = (w >> 1) * 64, wn = (w & 1) * 32;
  const int i16 = lane & 15, q4 = lane >> 4;
  const int part = n0 >> 10;               // block-uniform
  unsigned short* dst = (part == 0) ? Qw : ((part == 1) ? Kw : Vw);
  const float LN_THETA_OVER_HALF = 0.2878231366242558f;  // ln(10000)/32

#pragma unroll
  for (int ft = 0; ft < 2; ++ft) {
    const int nb0 = n0 + wn + ft * 16 + (q4 << 2);  // 4 consecutive features
    const int h  = (nb0 >> 6) & 15;
    const int d0 = nb0 & 63;
    const float invf0 = __expf(-(float)(d0 >> 1) * LN_THETA_OVER_HALF);
    const float invf1 = __expf(-(float)((d0 >> 1) + 1) * LN_THETA_OVER_HALF);
#pragma unroll
    for (int tt = 0; tt < 4; ++tt) {
      const int m = m0 + wm + tt * 16 + i16;
      const int b = m >> 11, s = m & 2047;
      float v0 = acc[ft][tt][0], v1 = acc[ft][tt][1];
      float v2 = acc[ft][tt][2], v3 = acc[ft][tt][3];
      if (part < 2) {
        float sn0, cs0, sn1, cs1;
        __sincosf((float)s * invf0, &sn0, &cs0);
        __sincosf((float)s * invf1, &sn1, &cs1);
        const float r0 = v0 * cs0 - v1 * sn0;
        const float r1 = v0 * sn0 + v1 * cs0;
        const float r2 = v2 * cs1 - v3 * sn1;
        const float r3 = v2 * sn1 + v3 * cs1;
        v0 = r0; v1 = r1; v2 = r2; v3 = r3;
        if (part == 0) { v0 *= 0.125f; v1 *= 0.125f; v2 *= 0.125f; v3 *= 0.125f; }
      }
      ushort4 pk;
      pk.x = f2bf(v0); pk.y = f2bf(v1); pk.z = f2bf(v2); pk.w = f2bf(v3);
      *(ushort4*)(dst + (((size_t)(b * NHEADS + h)) * SEQ + s) * DK + d0) = pk;
    }
  }
}

// ---------------------------------------------------------------------------
// Kernel 2: MFMA causal flash attention, S^T formulation, 128-key pairs,
// REGISTER-PREFETCH pipeline: global loads of pair pr+1 are issued right
// after barrier #2 and consumed (LDS write) only at the next loop top —
// the whole compute section hides the load latency. Fully-masked second
// half of the last pair (qb even) is skipped entirely (uniform guards).
// ---------------------------------------------------------------------------
__global__ __launch_bounds__(256, 4) void attn_mfma_kernel(
    const unsigned short* __restrict__ Q, const unsigned short* __restrict__ K,
    const unsigned short* __restrict__ V, unsigned short* __restrict__ O) {
  __shared__ __align__(16) unsigned short Ks[2][64 * 64];
  __shared__ __align__(16) unsigned short Vt[2][64 * 64];

  const int t = threadIdx.x, w = t >> 6, lane = t & 63;
  const int i16 = lane & 15, q4 = lane >> 4;
  const int bh = blockIdx.y;
  const int qb = gridDim.x - 1 - blockIdx.x;   // LPT: longest first
  const int q0 = qb * 64;
  const size_t base = (size_t)bh * SEQ * DK;

  bf16x8 qf0, qf1;
  {
    const unsigned short* qp = Q + base + (size_t)(q0 + w * 16 + i16) * DK + q4 * 8;
    qf0 = *(const bf16x8*)(qp);
    qf1 = *(const bf16x8*)(qp + 32);
  }

  f32x4 o_acc[4];
#pragma unroll
  for (int n = 0; n < 4; ++n) o_acc[n] = (f32x4){0.f, 0.f, 0.f, 0.f};
  float m_i = NEG_BIG, l_i = 0.f;

  const int krow = t >> 2;
  const int kc   = (t & 3) << 1;
  const int kr7  = krow & 7;
  const int vu   = t >> 7;            // which half this thread stages for V (wave-uniform)
  const int tl   = t & 127;
  const int vkq  = (tl & 15) << 2;
  const int vd8  = (tl >> 4) << 3;
  const int vg   = vkq >> 3;
  const int vh   = (vkq >> 2) & 1;

  const int npair = (qb >> 1) + 1;
  const bool lastDead = ((qb & 1) == 0);  // last pair's half-2 fully masked

  // ---- prefetch registers ----
  uint4 ka[2], kb[2];   // K halves, 2 chunks each
  uint4 vv[4];          // V rows for half vu
  {
    const bool dead = (npair == 1) && lastDead;
    const unsigned short* kp0 = K + base + (size_t)krow * DK + (kc << 3);
    ka[0] = *(const uint4*)kp0;
    kb[0] = *(const uint4*)(kp0 + 8);
    if (!dead) {
      const unsigned short* kp1 = K + base + (size_t)(64 + krow) * DK + (kc << 3);
      ka[1] = *(const uint4*)kp1;
      kb[1] = *(const uint4*)(kp1 + 8);
    }
    if (!(vu == 1 && dead)) {
      const unsigned short* vp = V + base + (size_t)(vu * 64 + vkq) * DK + vd8;
      vv[0] = *(const uint4*)(vp);
      vv[1] = *(const uint4*)(vp + DK);
      vv[2] = *(const uint4*)(vp + 2 * DK);
      vv[3] = *(const uint4*)(vp + 3 * DK);
    }
  }

  for (int pr = 0; pr < npair; ++pr) {
    const int kt2 = pr * 2;
    const bool dead = (pr == npair - 1) && lastDead;
    __syncthreads();
    // ---- regs -> LDS ----
    *(uint4*)(Ks[0] + krow * 64 + ((kc ^ kr7) << 3))       = ka[0];
    *(uint4*)(Ks[0] + krow * 64 + (((kc + 1) ^ kr7) << 3)) = kb[0];
    if (!dead) {
      *(uint4*)(Ks[1] + krow * 64 + ((kc ^ kr7) << 3))       = ka[1];
      *(uint4*)(Ks[1] + krow * 64 + (((kc + 1) ^ kr7) << 3)) = kb[1];
    }
    if (!(vu == 1 && dead)) {
      const unsigned short* a0 = (const unsigned short*)&vv[0];
      const unsigned short* a1 = (const unsigned short*)&vv[1];
      const unsigned short* a2 = (const unsigned short*)&vv[2];
      const unsigned short* a3 = (const unsigned short*)&vv[3];
#pragma unroll
      for (int j = 0; j < 8; ++j) {
        const int dk = vd8 + j;
        const int slot = vg ^ (dk & 7);
        ushort4 pk;
        pk.x = a0[j]; pk.y = a1[j]; pk.z = a2[j]; pk.w = a3[j];
        *(ushort4*)(Vt[vu] + dk * 64 + (slot << 3) + (vh << 2)) = pk;
      }
    }
    __syncthreads();

    // ---- issue prefetch of next pair (consumed next iteration) ----
    if (pr + 1 < npair) {
      const bool deadN = (pr + 2 == npair) && lastDead;
      const unsigned short* kp0 =
          K + base + (size_t)((kt2 + 2) * 64 + krow) * DK + (kc << 3);
      ka[0] = *(const uint4*)kp0;
      kb[0] = *(const uint4*)(kp0 + 8);
      if (!deadN) {
        const unsigned short* kp1 =
            K + base + (size_t)((kt2 + 3) * 64 + krow) * DK + (kc << 3);
        ka[1] = *(const uint4*)kp1;
        kb[1] = *(const uint4*)(kp1 + 8);
      }
      if (!(vu == 1 && deadN)) {
        const unsigned short* vp =
            V + base + (size_t)((kt2 + 2 + vu) * 64 + vkq) * DK + vd8;
        vv[0] = *(const uint4*)(vp);
        vv[1] = *(const uint4*)(vp + DK);
        vv[2] = *(const uint4*)(vp + 2 * DK);
        vv[3] = *(const uint4*)(vp + 3 * DK);
      }
    }

    // ---- S^T for both halves (dead half short-circuits to NEG_BIG) ----
    f32x4 s_acc[2][4];
#pragma unroll
    for (int mt = 0; mt < 4; ++mt) {
      const int key = mt * 16 + i16;
      const int k7 = key & 7;
      bf16x8 a0 = *(const bf16x8*)(Ks[0] + key * 64 + ((q4 ^ k7) << 3));
      bf16x8 a1 = *(const bf16x8*)(Ks[0] + key * 64 + (((4 + q4) ^ k7) << 3));
      f32x4 acc = (f32x4){0.f, 0.f, 0.f, 0.f};
      acc = __builtin_amdgcn_mfma_f32_16x16x32_bf16(a0, qf0, acc, 0, 0, 0);
      acc = __builtin_amdgcn_mfma_f32_16x16x32_bf16(a1, qf1, acc, 0, 0, 0);
      s_acc[0][mt] = acc;
    }
    if (!dead) {
#pragma unroll
      for (int mt = 0; mt < 4; ++mt) {
        const int key = mt * 16 + i16;
        const int k7 = key & 7;
        bf16x8 a0 = *(const bf16x8*)(Ks[1] + key * 64 + ((q4 ^ k7) << 3));
        bf16x8 a1 = *(const bf16x8*)(Ks[1] + key * 64 + (((4 + q4) ^ k7) << 3));
        f32x4 acc = (f32x4){0.f, 0.f, 0.f, 0.f};
        acc = __builtin_amdgcn_mfma_f32_16x16x32_bf16(a0, qf0, acc, 0, 0, 0);
        acc = __builtin_amdgcn_mfma_f32_16x16x32_bf16(a1, qf1, acc, 0, 0, 0);
        s_acc[1][mt] = acc;
      }
    } else {
#pragma unroll
      for (int mt = 0; mt < 4; ++mt)
        s_acc[1][mt] = (f32x4){NEG_BIG, NEG_BIG, NEG_BIG, NEG_BIG};
    }

    // ---- causal mask: last pair only (uniform branch) ----
    if (pr == npair - 1) {
      const int qrow = q0 + w * 16 + i16;
#pragma unroll
      for (int u = 0; u < 2; ++u) {
        const int kb2 = (kt2 + u) * 64 + q4 * 4;
#pragma unroll
        for (int mt = 0; mt < 4; ++mt)
#pragma unroll
          for (int r = 0; r < 4; ++r)
            if (kb2 + mt * 16 + r > qrow) s_acc[u][mt][r] = NEG_BIG;
      }
    }

    // ---- online softmax over 128 keys ----
    float tm = NEG_BIG;
#pragma unroll
    for (int u = 0; u < 2; ++u)
#pragma unroll
      for (int mt = 0; mt < 4; ++mt)
#pragma unroll
        for (int r = 0; r < 4; ++r) tm = fmaxf(tm, s_acc[u][mt][r]);
    tm = fmaxf(tm, __shfl_xor(tm, 16, 64));
    tm = fmaxf(tm, __shfl_xor(tm, 32, 64));
    const float m_new = fmaxf(m_i, tm);
    const float alpha = __expf(m_i - m_new);
    m_i = m_new;

    bf16x4 pf[2][4];
    float ls = 0.f;
#pragma unroll
    for (int u = 0; u < 2; ++u)
#pragma unroll
      for (int mt = 0; mt < 4; ++mt) {
        float p0 = __expf(s_acc[u][mt][0] - m_new);
        float p1 = __expf(s_acc[u][mt][1] - m_new);
        float p2 = __expf(s_acc[u][mt][2] - m_new);
        float p3 = __expf(s_acc[u][mt][3] - m_new);
        ls += (p0 + p1) + (p2 + p3);
        pf[u][mt][0] = (short)f2bf(p0);
        pf[u][mt][1] = (short)f2bf(p1);
        pf[u][mt][2] = (short)f2bf(p2);
        pf[u][mt][3] = (short)f2bf(p3);
      }
    ls += __shfl_xor(ls, 16, 64);
    ls += __shfl_xor(ls, 32, 64);
    l_i = l_i * alpha + ls;

    float a4[4];
#pragma unroll
    for (int r = 0; r < 4; ++r) a4[r] = __shfl(alpha, (q4 << 2) + r, 64);
#pragma unroll
    for (int n = 0; n < 4; ++n)
#pragma unroll
      for (int r = 0; r < 4; ++r) o_acc[n][r] *= a4[r];

    // ---- PV ----
#pragma unroll
    for (int mt = 0; mt < 4; ++mt) {
#pragma unroll
      for (int nt = 0; nt < 4; ++nt) {
        const int dk = nt * 16 + i16;
        const int slot = ((mt << 1) | (q4 >> 1)) ^ (dk & 7);
        bf16x4 vb = *(const bf16x4*)(Vt[0] + dk * 64 + (slot << 3) + ((q4 & 1) << 2));
        o_acc[nt] = mfma16x16x16(pf[0][mt], vb, o_acc[nt]);
      }
    }
    if (!dead) {
#pragma unroll
      for (int mt = 0; mt < 4; ++mt) {
#pragma unroll
        for (int nt = 0; nt < 4; ++nt) {
          const int dk = nt * 16 + i16;
          const int slot = ((mt << 1) | (q4 >> 1)) ^ (dk & 7);
          bf16x4 vb = *(const bf16x4*)(Vt[1] + dk * 64 + (slot << 3) + ((q4 & 1) << 2));
          o_acc[nt] = mfma16x16x16(pf[1][mt], vb, o_acc[nt]);
        }
      }
    }
  }

  const int b = bh >> 4, h = bh & 15;
#pragma unroll
  for (int r = 0; r < 4; ++r) {
    const float lr = __shfl(l_i, (q4 << 2) + r, 64);
    const float inv = 1.0f / lr;
    const int s = q0 + w * 16 + (q4 << 2) + r;
#pragma unroll
    for (int nt = 0; nt < 4; ++nt) {
      const int dk = nt * 16 + i16;
      O[((size_t)(b * SEQ + s)) * D_MODEL + h * DK + dk] = f2bf(o_acc[nt][r] * inv);
    }
  }
}

// ---------------------------------------------------------------------------
// Kernel 3: output projection -> fp32, float4 packed stores. grid (32, 16).
// ---------------------------------------------------------------------------
__global__ __launch_bounds__(256) void oproj_kernel(
    const unsigned short* __restrict__ ain, const unsigned short* __restrict__ wo,
    float* __restrict__ out) {
  __shared__ __align__(16) unsigned short As[128 * 32];
  __shared__ __align__(16) unsigned short Bs[64 * 32];
  f32x4 acc[2][4];
  const int m0 = blockIdx.x * 128;
  const int n0 = blockIdx.y * 64;
  gemm_bt_64T(ain, wo, m0, n0, As, Bs, acc);

  const int t = threadIdx.x, lane = t & 63, w = t >> 6;
  const int wm = (w >> 1) * 64, wn = (w & 1) * 32;
  const int i16 = lane & 15, q4 = lane >> 4;
#pragma unroll
  for (int ft = 0; ft < 2; ++ft) {
    const int nb0 = n0 + wn + ft * 16 + (q4 << 2);
#pragma unroll
    for (int tt = 0; tt < 4; ++tt) {
      const int m = m0 + wm + tt * 16 + i16;
      float4 v;
      v.x = acc[ft][tt][0]; v.y = acc[ft][tt][1];
      v.z = acc[ft][tt][2]; v.w = acc[ft][tt][3];
      *(float4*)(out + (size_t)m * D_MODEL + nb0) = v;
    }
  }
}

// ---------------------------------------------------------------------------
extern "C" void kernel_launch(void* const* d_in, const int* in_sizes, int n_in,
                              void* d_out, int out_size, void* d_ws, size_t ws_size,
                              hipStream_t stream) {
  const void* x    = d_in[0];
  const void* wqkv = d_in[2];
  const void* wo   = d_in[3];
  float* out = (float*)d_out;

  const size_t NTOK  = (size_t)NBATCH * SEQ * D_MODEL;  // 4,194,304 elements
  const size_t NWQKV = (size_t)3 * D_MODEL * D_MODEL;   // 3,145,728
  const size_t NWO   = (size_t)D_MODEL * D_MODEL;       // 1,048,576

  unsigned int*   flag = (unsigned int*)d_ws;
  unsigned short* base = (unsigned short*)((char*)d_ws + 16);
  unsigned short* Qw = base;                 // NTOK
  unsigned short* Kw = Qw + NTOK;            // NTOK
  unsigned short* Vw = Kw + NTOK;            // NTOK
  unsigned short* Aw = Vw + NTOK;            // NTOK (aliases xb; xb dead before attn writes)
  unsigned short* xb = Aw;                   // canonical bf16 x
  unsigned short* wq = Aw + NTOK;            // NWQKV (wo reuses after qkv done)
  unsigned short* wb = wq;                   // canonical bf16 wo

  dim3 blk(256);
  hipLaunchKernelGGL(sniff_kernel, dim3(1), blk, 0, stream,
                     (const unsigned short*)x, flag);
  hipLaunchKernelGGL(cvt_kernel, dim3((unsigned)(NTOK / 8 + 255) / 256), blk, 0, stream,
                     x, xb, (int)(NTOK / 8), flag);
  hipLaunchKernelGGL(cvt_kernel, dim3((unsigned)(NWQKV / 8 + 255) / 256), blk, 0, stream,
                     wqkv, wq, (int)(NWQKV / 8), flag);

  dim3 g1(32, 48);  // M/128 x 3072/64
  hipLaunchKernelGGL(qkv_rope_kernel, g1, blk, 0, stream, xb, wq, Qw, Kw, Vw);

  dim3 g2(SEQ / 64, NBATCH * NHEADS);
  hipLaunchKernelGGL(attn_mfma_kernel, g2, blk, 0, stream, Qw, Kw, Vw, Aw);

  hipLaunchKernelGGL(cvt_kernel, dim3((unsigned)(NWO / 8 + 255) / 256), blk, 0, stream,
                     wo, wb, (int)(NWO / 8), flag);

  dim3 g3(32, 16);  // M/128 x 1024/64
  hipLaunchKernelGGL(oproj_kernel, g3, blk, 0, stream, Aw, wb, out);
}

// Round 11
// 258.092 us; speedup vs baseline: 1.2385x; 1.2385x over previous
//
#include <hip/hip_runtime.h>
#include <cstdint>
#include <cstddef>

#define D_MODEL 1024
#define NHEADS  16
#define DK      64
#define SEQ     2048
#define NBATCH  2

#define NEG_BIG (-1e30f)

typedef __attribute__((ext_vector_type(8))) short bf16x8;
typedef __attribute__((ext_vector_type(4))) short bf16x4;
typedef __attribute__((ext_vector_type(4))) float f32x4;

// Host pass: amdgcn builtins unavailable -> guard on __AMDGCN__.
__device__ inline f32x4 mfma16x16x16(bf16x4 a, bf16x4 b, f32x4 c) {
#if defined(__AMDGCN__)
# if __has_builtin(__builtin_amdgcn_mfma_f32_16x16x16_bf16)
  return __builtin_amdgcn_mfma_f32_16x16x16_bf16(a, b, c, 0, 0, 0);
# else
  return __builtin_amdgcn_mfma_f32_16x16x16bf16_1k(a, b, c, 0, 0, 0);
# endif
#else
  (void)a; (void)b;
  return c;
#endif
}

__device__ inline void gll16(const unsigned short* g, unsigned short* l) {
#if defined(__AMDGCN__)
  __builtin_amdgcn_global_load_lds(
      (const __attribute__((address_space(1))) void*)g,
      (__attribute__((address_space(3))) void*)l, 16, 0, 0);
#else
  (void)g; (void)l;
#endif
}

__device__ inline unsigned short f2bf(float f) {
  unsigned int u = __float_as_uint(f);
  u += 0x7fffu + ((u >> 16) & 1u);   // round-to-nearest-even
  return (unsigned short)(u >> 16);
}

// ---------------------------------------------------------------------------
// Kernel 0: dtype sniffer (fp32 vs bf16 input buffers). flag=1 -> fp32.
// ---------------------------------------------------------------------------
__global__ __launch_bounds__(256) void sniff_kernel(
    const unsigned short* __restrict__ x, unsigned int* __restrict__ flag) {
  __shared__ int red[256];
  int cnt = 0;
  for (int j = threadIdx.x; j < 32768; j += 256) {
    const unsigned int u = x[2 * j];
    const unsigned int e = (u >> 7) & 0xFFu;
    cnt += (e >= 0x84u) ? 1 : 0;
  }
  red[threadIdx.x] = cnt;
  __syncthreads();
  for (int s = 128; s > 0; s >>= 1) {
    if (threadIdx.x < s) red[threadIdx.x] += red[threadIdx.x + s];
    __syncthreads();
  }
  if (threadIdx.x == 0) *flag = (red[0] > 100) ? 1u : 0u;
}

// ---------------------------------------------------------------------------
// Kernel 0b: canonicalize to bf16. n8 = element_count / 8.
// ---------------------------------------------------------------------------
__global__ __launch_bounds__(256) void cvt_kernel(
    const void* __restrict__ src, unsigned short* __restrict__ dst, int n8,
    const unsigned int* __restrict__ flag) {
  const int i = blockIdx.x * 256 + threadIdx.x;
  if (i >= n8) return;
  if (*flag != 0u) {
    const float4* s = (const float4*)src;
    float4 a = s[2 * i], b = s[2 * i + 1];
    uint4 r;
    r.x = (unsigned)f2bf(a.x) | ((unsigned)f2bf(a.y) << 16);
    r.y = (unsigned)f2bf(a.z) | ((unsigned)f2bf(a.w) << 16);
    r.z = (unsigned)f2bf(b.x) | ((unsigned)f2bf(b.y) << 16);
    r.w = (unsigned)f2bf(b.z) | ((unsigned)f2bf(b.w) << 16);
    ((uint4*)dst)[i] = r;
  } else {
    ((uint4*)dst)[i] = ((const uint4*)src)[i];
  }
}

// ---------------------------------------------------------------------------
// 128x64 tile GEMM mainloop, transposed-C, async staging (R9-verified).
// ---------------------------------------------------------------------------
__device__ inline void gemm_bt_64T(const unsigned short* __restrict__ A,
                                   const unsigned short* __restrict__ W,
                                   int m0, int n0,
                                   unsigned short* As, unsigned short* Bs,
                                   f32x4 acc[2][4]) {
  const int t    = threadIdx.x;
  const int lane = t & 63;
  const int w    = t >> 6;
  const int wm   = (w >> 1) * 64;   // token offset
  const int wn   = (w & 1) * 32;    // feature offset
  const int frow = lane & 15;
  const int fk   = (lane >> 4) * 8;

  for (int ft = 0; ft < 2; ++ft)
    for (int tt = 0; tt < 4; ++tt)
      acc[ft][tt] = (f32x4){0.f, 0.f, 0.f, 0.f};

  const int r0  = t >> 2;
  const int kc0 = (t & 3) << 3;

  for (int k0 = 0; k0 < 1024; k0 += 32) {
    __syncthreads();
    gll16(A + (size_t)(m0 + r0) * 1024 + k0 + kc0,      As + (size_t)t * 8);
    gll16(A + (size_t)(m0 + r0 + 64) * 1024 + k0 + kc0, As + (size_t)(t + 256) * 8);
    gll16(W + (size_t)(n0 + r0) * 1024 + k0 + kc0,      Bs + (size_t)t * 8);
    __syncthreads();

    bf16x8 xf[4], wf[2];
#pragma unroll
    for (int tt = 0; tt < 4; ++tt)
      xf[tt] = *(const bf16x8*)(As + (wm + tt * 16 + frow) * 32 + fk);
#pragma unroll
    for (int ft = 0; ft < 2; ++ft)
      wf[ft] = *(const bf16x8*)(Bs + (wn + ft * 16 + frow) * 32 + fk);
#pragma unroll
    for (int ft = 0; ft < 2; ++ft)
#pragma unroll
      for (int tt = 0; tt < 4; ++tt)
        acc[ft][tt] = __builtin_amdgcn_mfma_f32_16x16x32_bf16(wf[ft], xf[tt],
                                                              acc[ft][tt], 0, 0, 0);
  }
}

// ---------------------------------------------------------------------------
// Kernel 1: QKV projection + fused RoPE (in-register pairs), packed stores.
// ---------------------------------------------------------------------------
__global__ __launch_bounds__(256) void qkv_rope_kernel(
    const unsigned short* __restrict__ x,
    const unsigned short* __restrict__ wqkv,
    unsigned short* __restrict__ Qw, unsigned short* __restrict__ Kw,
    unsigned short* __restrict__ Vw) {
  __shared__ __align__(16) unsigned short As[128 * 32];
  __shared__ __align__(16) unsigned short Bs[64 * 32];
  f32x4 acc[2][4];
  const int m0 = blockIdx.x * 128;
  const int n0 = blockIdx.y * 64;
  gemm_bt_64T(x, wqkv, m0, n0, As, Bs, acc);

  const int t = threadIdx.x, lane = t & 63, w = t >> 6;
  const int wm = (w >> 1) * 64, wn = (w & 1) * 32;
  const int i16 = lane & 15, q4 = lane >> 4;
  const int part = n0 >> 10;               // block-uniform
  unsigned short* dst = (part == 0) ? Qw : ((part == 1) ? Kw : Vw);
  const float LN_THETA_OVER_HALF = 0.2878231366242558f;  // ln(10000)/32

#pragma unroll
  for (int ft = 0; ft < 2; ++ft) {
    const int nb0 = n0 + wn + ft * 16 + (q4 << 2);  // 4 consecutive features
    const int h  = (nb0 >> 6) & 15;
    const int d0 = nb0 & 63;
    const float invf0 = __expf(-(float)(d0 >> 1) * LN_THETA_OVER_HALF);
    const float invf1 = __expf(-(float)((d0 >> 1) + 1) * LN_THETA_OVER_HALF);
#pragma unroll
    for (int tt = 0; tt < 4; ++tt) {
      const int m = m0 + wm + tt * 16 + i16;
      const int b = m >> 11, s = m & 2047;
      float v0 = acc[ft][tt][0], v1 = acc[ft][tt][1];
      float v2 = acc[ft][tt][2], v3 = acc[ft][tt][3];
      if (part < 2) {
        float sn0, cs0, sn1, cs1;
        __sincosf((float)s * invf0, &sn0, &cs0);
        __sincosf((float)s * invf1, &sn1, &cs1);
        const float r0 = v0 * cs0 - v1 * sn0;
        const float r1 = v0 * sn0 + v1 * cs0;
        const float r2 = v2 * cs1 - v3 * sn1;
        const float r3 = v2 * sn1 + v3 * cs1;
        v0 = r0; v1 = r1; v2 = r2; v3 = r3;
        if (part == 0) { v0 *= 0.125f; v1 *= 0.125f; v2 *= 0.125f; v3 *= 0.125f; }
      }
      ushort4 pk;
      pk.x = f2bf(v0); pk.y = f2bf(v1); pk.z = f2bf(v2); pk.w = f2bf(v3);
      *(ushort4*)(dst + (((size_t)(b * NHEADS + h)) * SEQ + s) * DK + d0) = pk;
    }
  }
}

// ---------------------------------------------------------------------------
// Per-128-key attention step for one q-tile (S^T formulation, R8-verified).
// ---------------------------------------------------------------------------
__device__ __forceinline__ void attn_step(
    const unsigned short* Ks0, const unsigned short* Ks1,
    const unsigned short* Vt0, const unsigned short* Vt1,
    bf16x8 qf0, bf16x8 qf1, int i16, int q4, int w,
    int q0t, int kt2, bool domask,
    float& m_i, float& l_i, f32x4 o_acc[4]) {
  // ---- S^T for both halves ----
  f32x4 s_acc[2][4];
#pragma unroll
  for (int u = 0; u < 2; ++u) {
    const unsigned short* Ksu = u ? Ks1 : Ks0;
#pragma unroll
    for (int mt = 0; mt < 4; ++mt) {
      const int key = mt * 16 + i16;
      const int k7 = key & 7;
      bf16x8 a0 = *(const bf16x8*)(Ksu + key * 64 + ((q4 ^ k7) << 3));
      bf16x8 a1 = *(const bf16x8*)(Ksu + key * 64 + (((4 + q4) ^ k7) << 3));
      f32x4 acc = (f32x4){0.f, 0.f, 0.f, 0.f};
      acc = __builtin_amdgcn_mfma_f32_16x16x32_bf16(a0, qf0, acc, 0, 0, 0);
      acc = __builtin_amdgcn_mfma_f32_16x16x32_bf16(a1, qf1, acc, 0, 0, 0);
      s_acc[u][mt] = acc;
    }
  }

  // ---- causal mask on final pair of this tile (block-uniform branch) ----
  if (domask) {
    const int qrow = q0t + w * 16 + i16;
#pragma unroll
    for (int u = 0; u < 2; ++u) {
      const int kb2 = (kt2 + u) * 64 + q4 * 4;
#pragma unroll
      for (int mt = 0; mt < 4; ++mt)
#pragma unroll
        for (int r = 0; r < 4; ++r)
          if (kb2 + mt * 16 + r > qrow) s_acc[u][mt][r] = NEG_BIG;
    }
  }

  // ---- online softmax over 128 keys ----
  float tm = NEG_BIG;
#pragma unroll
  for (int u = 0; u < 2; ++u)
#pragma unroll
    for (int mt = 0; mt < 4; ++mt)
#pragma unroll
      for (int r = 0; r < 4; ++r) tm = fmaxf(tm, s_acc[u][mt][r]);
  tm = fmaxf(tm, __shfl_xor(tm, 16, 64));
  tm = fmaxf(tm, __shfl_xor(tm, 32, 64));
  const float m_new = fmaxf(m_i, tm);
  const float alpha = __expf(m_i - m_new);
  m_i = m_new;

  bf16x4 pf[2][4];
  float ls = 0.f;
#pragma unroll
  for (int u = 0; u < 2; ++u)
#pragma unroll
    for (int mt = 0; mt < 4; ++mt) {
      float p0 = __expf(s_acc[u][mt][0] - m_new);
      float p1 = __expf(s_acc[u][mt][1] - m_new);
      float p2 = __expf(s_acc[u][mt][2] - m_new);
      float p3 = __expf(s_acc[u][mt][3] - m_new);
      ls += (p0 + p1) + (p2 + p3);
      pf[u][mt][0] = (short)f2bf(p0);
      pf[u][mt][1] = (short)f2bf(p1);
      pf[u][mt][2] = (short)f2bf(p2);
      pf[u][mt][3] = (short)f2bf(p3);
    }
  ls += __shfl_xor(ls, 16, 64);
  ls += __shfl_xor(ls, 32, 64);
  l_i = l_i * alpha + ls;

  float a4[4];
#pragma unroll
  for (int r = 0; r < 4; ++r) a4[r] = __shfl(alpha, (q4 << 2) + r, 64);
#pragma unroll
  for (int n = 0; n < 4; ++n)
#pragma unroll
    for (int r = 0; r < 4; ++r) o_acc[n][r] *= a4[r];

  // ---- PV over both halves ----
#pragma unroll
  for (int u = 0; u < 2; ++u) {
    const unsigned short* Vtu = u ? Vt1 : Vt0;
#pragma unroll
    for (int mt = 0; mt < 4; ++mt) {
#pragma unroll
      for (int nt = 0; nt < 4; ++nt) {
        const int dk = nt * 16 + i16;
        const int slot = ((mt << 1) | (q4 >> 1)) ^ (dk & 7);
        bf16x4 vb = *(const bf16x4*)(Vtu + dk * 64 + (slot << 3) + ((q4 & 1) << 2));
        o_acc[nt] = mfma16x16x16(pf[u][mt], vb, o_acc[nt]);
      }
    }
  }
}

// ---------------------------------------------------------------------------
// Kernel 2: MFMA causal flash attention, S^T formulation, 128-key pairs,
// TWO q-tiles per block (qbA = bx, qbB = 31-bx): uniform total work per
// block (no triangular tail) and each K/V staging feeds both tiles.
// grid = (SEQ/128, B*H) = (16, 32).
// ---------------------------------------------------------------------------
__global__ __launch_bounds__(256) void attn_mfma_kernel(
    const unsigned short* __restrict__ Q, const unsigned short* __restrict__ K,
    const unsigned short* __restrict__ V, unsigned short* __restrict__ O) {
  __shared__ __align__(16) unsigned short Ks[2][64 * 64];
  __shared__ __align__(16) unsigned short Vt[2][64 * 64];

  const int t = threadIdx.x, w = t >> 6, lane = t & 63;
  const int i16 = lane & 15, q4 = lane >> 4;
  const int bh = blockIdx.y;
  const int qbA = blockIdx.x;              // short tile: 0..15
  const int qbB = 31 - blockIdx.x;         // long tile: 16..31
  const int q0A = qbA * 64, q0B = qbB * 64;
  const size_t base = (size_t)bh * SEQ * DK;

  bf16x8 qfA0, qfA1, qfB0, qfB1;
  {
    const unsigned short* qpA = Q + base + (size_t)(q0A + w * 16 + i16) * DK + q4 * 8;
    qfA0 = *(const bf16x8*)(qpA);
    qfA1 = *(const bf16x8*)(qpA + 32);
    const unsigned short* qpB = Q + base + (size_t)(q0B + w * 16 + i16) * DK + q4 * 8;
    qfB0 = *(const bf16x8*)(qpB);
    qfB1 = *(const bf16x8*)(qpB + 32);
  }

  f32x4 oA[4], oB[4];
#pragma unroll
  for (int n = 0; n < 4; ++n) {
    oA[n] = (f32x4){0.f, 0.f, 0.f, 0.f};
    oB[n] = (f32x4){0.f, 0.f, 0.f, 0.f};
  }
  float mA = NEG_BIG, lA = 0.f, mB = NEG_BIG, lB = 0.f;

  const int krow = t >> 2;
  const int kc   = (t & 3) << 1;
  const int kr7  = krow & 7;
  const int vu   = t >> 7;            // which half this thread stages for V
  const int tl   = t & 127;
  const int vkq  = (tl & 15) << 2;
  const int vd8  = (tl >> 4) << 3;
  const int vg   = vkq >> 3;
  const int vh   = (vkq >> 2) & 1;

  const int npairA = (qbA >> 1) + 1;
  const int npairB = (qbB >> 1) + 1;

  for (int pr = 0; pr < npairB; ++pr) {
    const int kt2 = pr * 2;
    __syncthreads();
    // ---- stage K, both halves ----
#pragma unroll
    for (int u = 0; u < 2; ++u) {
      const unsigned short* kp =
          K + base + (size_t)((kt2 + u) * 64 + krow) * DK + (kc << 3);
      uint4 k0 = *(const uint4*)kp;
      uint4 k1 = *(const uint4*)(kp + 8);
      *(uint4*)(Ks[u] + krow * 64 + ((kc ^ kr7) << 3))       = k0;
      *(uint4*)(Ks[u] + krow * 64 + (((kc + 1) ^ kr7) << 3)) = k1;
    }
    // ---- stage V transposed, half vu per thread ----
    {
      const unsigned short* vp =
          V + base + (size_t)((kt2 + vu) * 64 + vkq) * DK + vd8;
      uint4 u0 = *(const uint4*)(vp);
      uint4 u1 = *(const uint4*)(vp + DK);
      uint4 u2 = *(const uint4*)(vp + 2 * DK);
      uint4 u3 = *(const uint4*)(vp + 3 * DK);
      const unsigned short* a0 = (const unsigned short*)&u0;
      const unsigned short* a1 = (const unsigned short*)&u1;
      const unsigned short* a2 = (const unsigned short*)&u2;
      const unsigned short* a3 = (const unsigned short*)&u3;
#pragma unroll
      for (int j = 0; j < 8; ++j) {
        const int dk = vd8 + j;
        const int slot = vg ^ (dk & 7);
        ushort4 pk;
        pk.x = a0[j]; pk.y = a1[j]; pk.z = a2[j]; pk.w = a3[j];
        *(ushort4*)(Vt[vu] + dk * 64 + (slot << 3) + (vh << 2)) = pk;
      }
    }
    __syncthreads();

    // ---- long tile always; short tile while in range (uniform branches) ----
    attn_step(Ks[0], Ks[1], Vt[0], Vt[1], qfB0, qfB1, i16, q4, w,
              q0B, kt2, pr == npairB - 1, mB, lB, oB);
    if (pr < npairA)
      attn_step(Ks[0], Ks[1], Vt[0], Vt[1], qfA0, qfA1, i16, q4, w,
                q0A, kt2, pr == npairA - 1, mA, lA, oA);
  }

  // ---- epilogues ----
  const int b = bh >> 4, h = bh & 15;
#pragma unroll
  for (int r = 0; r < 4; ++r) {
    const float lrA = __shfl(lA, (q4 << 2) + r, 64);
    const float lrB = __shfl(lB, (q4 << 2) + r, 64);
    const float invA = 1.0f / lrA;
    const float invB = 1.0f / lrB;
    const int sA = q0A + w * 16 + (q4 << 2) + r;
    const int sB = q0B + w * 16 + (q4 << 2) + r;
#pragma unroll
    for (int nt = 0; nt < 4; ++nt) {
      const int dk = nt * 16 + i16;
      O[((size_t)(b * SEQ + sA)) * D_MODEL + h * DK + dk] = f2bf(oA[nt][r] * invA);
      O[((size_t)(b * SEQ + sB)) * D_MODEL + h * DK + dk] = f2bf(oB[nt][r] * invB);
    }
  }
}

// ---------------------------------------------------------------------------
// Kernel 3: output projection -> fp32, float4 packed stores. grid (32, 16).
// ---------------------------------------------------------------------------
__global__ __launch_bounds__(256) void oproj_kernel(
    const unsigned short* __restrict__ ain, const unsigned short* __restrict__ wo,
    float* __restrict__ out) {
  __shared__ __align__(16) unsigned short As[128 * 32];
  __shared__ __align__(16) unsigned short Bs[64 * 32];
  f32x4 acc[2][4];
  const int m0 = blockIdx.x * 128;
  const int n0 = blockIdx.y * 64;
  gemm_bt_64T(ain, wo, m0, n0, As, Bs, acc);

  const int t = threadIdx.x, lane = t & 63, w = t >> 6;
  const int wm = (w >> 1) * 64, wn = (w & 1) * 32;
  const int i16 = lane & 15, q4 = lane >> 4;
#pragma unroll
  for (int ft = 0; ft < 2; ++ft) {
    const int nb0 = n0 + wn + ft * 16 + (q4 << 2);
#pragma unroll
    for (int tt = 0; tt < 4; ++tt) {
      const int m = m0 + wm + tt * 16 + i16;
      float4 v;
      v.x = acc[ft][tt][0]; v.y = acc[ft][tt][1];
      v.z = acc[ft][tt][2]; v.w = acc[ft][tt][3];
      *(float4*)(out + (size_t)m * D_MODEL + nb0) = v;
    }
  }
}

// ---------------------------------------------------------------------------
extern "C" void kernel_launch(void* const* d_in, const int* in_sizes, int n_in,
                              void* d_out, int out_size, void* d_ws, size_t ws_size,
                              hipStream_t stream) {
  const void* x    = d_in[0];
  const void* wqkv = d_in[2];
  const void* wo   = d_in[3];
  float* out = (float*)d_out;

  const size_t NTOK  = (size_t)NBATCH * SEQ * D_MODEL;  // 4,194,304 elements
  const size_t NWQKV = (size_t)3 * D_MODEL * D_MODEL;   // 3,145,728
  const size_t NWO   = (size_t)D_MODEL * D_MODEL;       // 1,048,576

  unsigned int*   flag = (unsigned int*)d_ws;
  unsigned short* base = (unsigned short*)((char*)d_ws + 16);
  unsigned short* Qw = base;                 // NTOK
  unsigned short* Kw = Qw + NTOK;            // NTOK
  unsigned short* Vw = Kw + NTOK;            // NTOK
  unsigned short* Aw = Vw + NTOK;            // NTOK (aliases xb; xb dead before attn writes)
  unsigned short* xb = Aw;                   // canonical bf16 x
  unsigned short* wq = Aw + NTOK;            // NWQKV (wo reuses after qkv done)
  unsigned short* wb = wq;                   // canonical bf16 wo

  dim3 blk(256);
  hipLaunchKernelGGL(sniff_kernel, dim3(1), blk, 0, stream,
                     (const unsigned short*)x, flag);
  hipLaunchKernelGGL(cvt_kernel, dim3((unsigned)(NTOK / 8 + 255) / 256), blk, 0, stream,
                     x, xb, (int)(NTOK / 8), flag);
  hipLaunchKernelGGL(cvt_kernel, dim3((unsigned)(NWQKV / 8 + 255) / 256), blk, 0, stream,
                     wqkv, wq, (int)(NWQKV / 8), flag);

  dim3 g1(32, 48);  // M/128 x 3072/64
  hipLaunchKernelGGL(qkv_rope_kernel, g1, blk, 0, stream, xb, wq, Qw, Kw, Vw);

  dim3 g2(SEQ / 128, NBATCH * NHEADS);  // paired q-tiles: uniform work
  hipLaunchKernelGGL(attn_mfma_kernel, g2, blk, 0, stream, Qw, Kw, Vw, Aw);

  hipLaunchKernelGGL(cvt_kernel, dim3((unsigned)(NWO / 8 + 255) / 256), blk, 0, stream,
                     wo, wb, (int)(NWO / 8), flag);

  dim3 g3(32, 16);  // M/128 x 1024/64
  hipLaunchKernelGGL(oproj_kernel, g3, blk, 0, stream, Aw, wb, out);
}

// Round 12
// 235.019 us; speedup vs baseline: 1.3601x; 1.0982x over previous
//
#include <hip/hip_runtime.h>
#include <cstdint>
#include <cstddef>

#define D_MODEL 1024
#define NHEADS  16
#define DK      64
#define SEQ     2048
#define NBATCH  2

#define NEG_BIG (-1e30f)

typedef __attribute__((ext_vector_type(8))) short bf16x8;
typedef __attribute__((ext_vector_type(4))) short bf16x4;
typedef __attribute__((ext_vector_type(4))) float f32x4;

// Host pass: amdgcn builtins unavailable -> guard on __AMDGCN__.
__device__ inline f32x4 mfma16x16x16(bf16x4 a, bf16x4 b, f32x4 c) {
#if defined(__AMDGCN__)
# if __has_builtin(__builtin_amdgcn_mfma_f32_16x16x16_bf16)
  return __builtin_amdgcn_mfma_f32_16x16x16_bf16(a, b, c, 0, 0, 0);
# else
  return __builtin_amdgcn_mfma_f32_16x16x16bf16_1k(a, b, c, 0, 0, 0);
# endif
#else
  (void)a; (void)b;
  return c;
#endif
}

__device__ inline void gll16(const unsigned short* g, unsigned short* l) {
#if defined(__AMDGCN__)
  __builtin_amdgcn_global_load_lds(
      (const __attribute__((address_space(1))) void*)g,
      (__attribute__((address_space(3))) void*)l, 16, 0, 0);
#else
  (void)g; (void)l;
#endif
}

__device__ inline unsigned short f2bf(float f) {
  unsigned int u = __float_as_uint(f);
  u += 0x7fffu + ((u >> 16) & 1u);   // round-to-nearest-even
  return (unsigned short)(u >> 16);
}

// ---------------------------------------------------------------------------
// Kernel 0: dtype sniffer (fp32 vs bf16 input buffers). flag=1 -> fp32.
// ---------------------------------------------------------------------------
__global__ __launch_bounds__(256) void sniff_kernel(
    const unsigned short* __restrict__ x, unsigned int* __restrict__ flag) {
  __shared__ int red[256];
  int cnt = 0;
  for (int j = threadIdx.x; j < 32768; j += 256) {
    const unsigned int u = x[2 * j];
    const unsigned int e = (u >> 7) & 0xFFu;
    cnt += (e >= 0x84u) ? 1 : 0;
  }
  red[threadIdx.x] = cnt;
  __syncthreads();
  for (int s = 128; s > 0; s >>= 1) {
    if (threadIdx.x < s) red[threadIdx.x] += red[threadIdx.x + s];
    __syncthreads();
  }
  if (threadIdx.x == 0) *flag = (red[0] > 100) ? 1u : 0u;
}

// ---------------------------------------------------------------------------
// Kernel 0b: canonicalize to bf16. n8 = element_count / 8.
// ---------------------------------------------------------------------------
__global__ __launch_bounds__(256) void cvt_kernel(
    const void* __restrict__ src, unsigned short* __restrict__ dst, int n8,
    const unsigned int* __restrict__ flag) {
  const int i = blockIdx.x * 256 + threadIdx.x;
  if (i >= n8) return;
  if (*flag != 0u) {
    const float4* s = (const float4*)src;
    float4 a = s[2 * i], b = s[2 * i + 1];
    uint4 r;
    r.x = (unsigned)f2bf(a.x) | ((unsigned)f2bf(a.y) << 16);
    r.y = (unsigned)f2bf(a.z) | ((unsigned)f2bf(a.w) << 16);
    r.z = (unsigned)f2bf(b.x) | ((unsigned)f2bf(b.y) << 16);
    r.w = (unsigned)f2bf(b.z) | ((unsigned)f2bf(b.w) << 16);
    ((uint4*)dst)[i] = r;
  } else {
    ((uint4*)dst)[i] = ((const uint4*)src)[i];
  }
}

// ---------------------------------------------------------------------------
// 128x64 tile GEMM mainloop, transposed-C, BK=64, async staging with
// SOURCE-PERMUTED global_load_lds: lane fetches granule (t&7)^(row&7) so
// the fixed dest layout lands XOR-swizzled -> conflict-free b128 frag reads
// (8 balanced bank-quads, 2 lanes/bank). Coalescing unchanged (each 8-thread
// row group still covers one contiguous 128B segment).
// LDS rows of 128B: As[128][64], Bs[64][64] (bf16). 16 K-iterations.
// ---------------------------------------------------------------------------
__device__ inline void gemm_bt_64T(const unsigned short* __restrict__ A,
                                   const unsigned short* __restrict__ W,
                                   int m0, int n0,
                                   unsigned short* As, unsigned short* Bs,
                                   f32x4 acc[2][4]) {
  const int t    = threadIdx.x;
  const int lane = t & 63;
  const int w    = t >> 6;
  const int wm   = (w >> 1) * 64;   // token offset
  const int wn   = (w & 1) * 32;    // feature offset
  const int frow = lane & 15;
  const int q4   = lane >> 4;       // granule base (0..3)

  for (int ft = 0; ft < 2; ++ft)
    for (int tt = 0; tt < 4; ++tt)
      acc[ft][tt] = (f32x4){0.f, 0.f, 0.f, 0.f};

  const int srow  = t >> 3;         // 0..31 (row within 32-row chunk)
  const int gslot = t & 7;          // dest granule slot

  for (int k0 = 0; k0 < 1024; k0 += 64) {
    __syncthreads();
#pragma unroll
    for (int c = 0; c < 4; ++c) {   // A: 4 chunks x 32 rows
      const int row = c * 32 + srow;
      const int gsrc = gslot ^ (row & 7);
      gll16(A + (size_t)(m0 + row) * 1024 + k0 + gsrc * 8,
            As + ((size_t)t + 256 * c) * 8);
    }
#pragma unroll
    for (int c = 0; c < 2; ++c) {   // B: 2 chunks x 32 rows
      const int row = c * 32 + srow;
      const int gsrc = gslot ^ (row & 7);
      gll16(W + (size_t)(n0 + row) * 1024 + k0 + gsrc * 8,
            Bs + ((size_t)t + 256 * c) * 8);
    }
    __syncthreads();

#pragma unroll
    for (int kk = 0; kk < 2; ++kk) {
      const int gg = q4 + kk * 4;   // wanted global granule
      bf16x8 xv[4], wv[2];
#pragma unroll
      for (int tt = 0; tt < 4; ++tt) {
        const int row = wm + tt * 16 + frow;
        xv[tt] = *(const bf16x8*)(As + row * 64 + (gg ^ (row & 7)) * 8);
      }
#pragma unroll
      for (int ft = 0; ft < 2; ++ft) {
        const int row = wn + ft * 16 + frow;
        wv[ft] = *(const bf16x8*)(Bs + row * 64 + (gg ^ (row & 7)) * 8);
      }
#pragma unroll
      for (int ft = 0; ft < 2; ++ft)
#pragma unroll
        for (int tt = 0; tt < 4; ++tt)
          acc[ft][tt] = __builtin_amdgcn_mfma_f32_16x16x32_bf16(wv[ft], xv[tt],
                                                                acc[ft][tt], 0, 0, 0);
    }
  }
}

// ---------------------------------------------------------------------------
// Kernel 1: QKV projection + fused RoPE (in-register pairs), packed stores.
// ---------------------------------------------------------------------------
__global__ __launch_bounds__(256) void qkv_rope_kernel(
    const unsigned short* __restrict__ x,
    const unsigned short* __restrict__ wqkv,
    unsigned short* __restrict__ Qw, unsigned short* __restrict__ Kw,
    unsigned short* __restrict__ Vw) {
  __shared__ __align__(16) unsigned short As[128 * 64];
  __shared__ __align__(16) unsigned short Bs[64 * 64];
  f32x4 acc[2][4];
  const int m0 = blockIdx.x * 128;
  const int n0 = blockIdx.y * 64;
  gemm_bt_64T(x, wqkv, m0, n0, As, Bs, acc);

  const int t = threadIdx.x, lane = t & 63, w = t >> 6;
  const int wm = (w >> 1) * 64, wn = (w & 1) * 32;
  const int i16 = lane & 15, q4 = lane >> 4;
  const int part = n0 >> 10;               // block-uniform
  unsigned short* dst = (part == 0) ? Qw : ((part == 1) ? Kw : Vw);
  const float LN_THETA_OVER_HALF = 0.2878231366242558f;  // ln(10000)/32

#pragma unroll
  for (int ft = 0; ft < 2; ++ft) {
    const int nb0 = n0 + wn + ft * 16 + (q4 << 2);  // 4 consecutive features
    const int h  = (nb0 >> 6) & 15;
    const int d0 = nb0 & 63;
    const float invf0 = __expf(-(float)(d0 >> 1) * LN_THETA_OVER_HALF);
    const float invf1 = __expf(-(float)((d0 >> 1) + 1) * LN_THETA_OVER_HALF);
#pragma unroll
    for (int tt = 0; tt < 4; ++tt) {
      const int m = m0 + wm + tt * 16 + i16;
      const int b = m >> 11, s = m & 2047;
      float v0 = acc[ft][tt][0], v1 = acc[ft][tt][1];
      float v2 = acc[ft][tt][2], v3 = acc[ft][tt][3];
      if (part < 2) {
        float sn0, cs0, sn1, cs1;
        __sincosf((float)s * invf0, &sn0, &cs0);
        __sincosf((float)s * invf1, &sn1, &cs1);
        const float r0 = v0 * cs0 - v1 * sn0;
        const float r1 = v0 * sn0 + v1 * cs0;
        const float r2 = v2 * cs1 - v3 * sn1;
        const float r3 = v2 * sn1 + v3 * cs1;
        v0 = r0; v1 = r1; v2 = r2; v3 = r3;
        if (part == 0) { v0 *= 0.125f; v1 *= 0.125f; v2 *= 0.125f; v3 *= 0.125f; }
      }
      ushort4 pk;
      pk.x = f2bf(v0); pk.y = f2bf(v1); pk.z = f2bf(v2); pk.w = f2bf(v3);
      *(ushort4*)(dst + (((size_t)(b * NHEADS + h)) * SEQ + s) * DK + d0) = pk;
    }
  }
}

// ---------------------------------------------------------------------------
// Per-128-key attention step for one q-tile (S^T formulation, R8-verified).
// ---------------------------------------------------------------------------
__device__ __forceinline__ void attn_step(
    const unsigned short* Ks0, const unsigned short* Ks1,
    const unsigned short* Vt0, const unsigned short* Vt1,
    bf16x8 qf0, bf16x8 qf1, int i16, int q4, int w,
    int q0t, int kt2, bool domask,
    float& m_i, float& l_i, f32x4 o_acc[4]) {
  // ---- S^T for both halves ----
  f32x4 s_acc[2][4];
#pragma unroll
  for (int u = 0; u < 2; ++u) {
    const unsigned short* Ksu = u ? Ks1 : Ks0;
#pragma unroll
    for (int mt = 0; mt < 4; ++mt) {
      const int key = mt * 16 + i16;
      const int k7 = key & 7;
      bf16x8 a0 = *(const bf16x8*)(Ksu + key * 64 + ((q4 ^ k7) << 3));
      bf16x8 a1 = *(const bf16x8*)(Ksu + key * 64 + (((4 + q4) ^ k7) << 3));
      f32x4 acc = (f32x4){0.f, 0.f, 0.f, 0.f};
      acc = __builtin_amdgcn_mfma_f32_16x16x32_bf16(a0, qf0, acc, 0, 0, 0);
      acc = __builtin_amdgcn_mfma_f32_16x16x32_bf16(a1, qf1, acc, 0, 0, 0);
      s_acc[u][mt] = acc;
    }
  }

  // ---- causal mask on final pair of this tile (block-uniform branch) ----
  if (domask) {
    const int qrow = q0t + w * 16 + i16;
#pragma unroll
    for (int u = 0; u < 2; ++u) {
      const int kb2 = (kt2 + u) * 64 + q4 * 4;
#pragma unroll
      for (int mt = 0; mt < 4; ++mt)
#pragma unroll
        for (int r = 0; r < 4; ++r)
          if (kb2 + mt * 16 + r > qrow) s_acc[u][mt][r] = NEG_BIG;
    }
  }

  // ---- online softmax over 128 keys ----
  float tm = NEG_BIG;
#pragma unroll
  for (int u = 0; u < 2; ++u)
#pragma unroll
    for (int mt = 0; mt < 4; ++mt)
#pragma unroll
      for (int r = 0; r < 4; ++r) tm = fmaxf(tm, s_acc[u][mt][r]);
  tm = fmaxf(tm, __shfl_xor(tm, 16, 64));
  tm = fmaxf(tm, __shfl_xor(tm, 32, 64));
  const float m_new = fmaxf(m_i, tm);
  const float alpha = __expf(m_i - m_new);
  m_i = m_new;

  bf16x4 pf[2][4];
  float ls = 0.f;
#pragma unroll
  for (int u = 0; u < 2; ++u)
#pragma unroll
    for (int mt = 0; mt < 4; ++mt) {
      float p0 = __expf(s_acc[u][mt][0] - m_new);
      float p1 = __expf(s_acc[u][mt][1] - m_new);
      float p2 = __expf(s_acc[u][mt][2] - m_new);
      float p3 = __expf(s_acc[u][mt][3] - m_new);
      ls += (p0 + p1) + (p2 + p3);
      pf[u][mt][0] = (short)f2bf(p0);
      pf[u][mt][1] = (short)f2bf(p1);
      pf[u][mt][2] = (short)f2bf(p2);
      pf[u][mt][3] = (short)f2bf(p3);
    }
  ls += __shfl_xor(ls, 16, 64);
  ls += __shfl_xor(ls, 32, 64);
  l_i = l_i * alpha + ls;

  float a4[4];
#pragma unroll
  for (int r = 0; r < 4; ++r) a4[r] = __shfl(alpha, (q4 << 2) + r, 64);
#pragma unroll
  for (int n = 0; n < 4; ++n)
#pragma unroll
    for (int r = 0; r < 4; ++r) o_acc[n][r] *= a4[r];

  // ---- PV over both halves ----
#pragma unroll
  for (int u = 0; u < 2; ++u) {
    const unsigned short* Vtu = u ? Vt1 : Vt0;
#pragma unroll
    for (int mt = 0; mt < 4; ++mt) {
#pragma unroll
      for (int nt = 0; nt < 4; ++nt) {
        const int dk = nt * 16 + i16;
        const int slot = ((mt << 1) | (q4 >> 1)) ^ (dk & 7);
        bf16x4 vb = *(const bf16x4*)(Vtu + dk * 64 + (slot << 3) + ((q4 & 1) << 2));
        o_acc[nt] = mfma16x16x16(pf[u][mt], vb, o_acc[nt]);
      }
    }
  }
}

// ---------------------------------------------------------------------------
// Kernel 2: MFMA causal flash attention, S^T, 128-key pairs, TWO q-tiles
// per block (uniform work, staging shared). grid = (SEQ/128, B*H).
// ---------------------------------------------------------------------------
__global__ __launch_bounds__(256) void attn_mfma_kernel(
    const unsigned short* __restrict__ Q, const unsigned short* __restrict__ K,
    const unsigned short* __restrict__ V, unsigned short* __restrict__ O) {
  __shared__ __align__(16) unsigned short Ks[2][64 * 64];
  __shared__ __align__(16) unsigned short Vt[2][64 * 64];

  const int t = threadIdx.x, w = t >> 6, lane = t & 63;
  const int i16 = lane & 15, q4 = lane >> 4;
  const int bh = blockIdx.y;
  const int qbA = blockIdx.x;              // short tile: 0..15
  const int qbB = 31 - blockIdx.x;         // long tile: 16..31
  const int q0A = qbA * 64, q0B = qbB * 64;
  const size_t base = (size_t)bh * SEQ * DK;

  bf16x8 qfA0, qfA1, qfB0, qfB1;
  {
    const unsigned short* qpA = Q + base + (size_t)(q0A + w * 16 + i16) * DK + q4 * 8;
    qfA0 = *(const bf16x8*)(qpA);
    qfA1 = *(const bf16x8*)(qpA + 32);
    const unsigned short* qpB = Q + base + (size_t)(q0B + w * 16 + i16) * DK + q4 * 8;
    qfB0 = *(const bf16x8*)(qpB);
    qfB1 = *(const bf16x8*)(qpB + 32);
  }

  f32x4 oA[4], oB[4];
#pragma unroll
  for (int n = 0; n < 4; ++n) {
    oA[n] = (f32x4){0.f, 0.f, 0.f, 0.f};
    oB[n] = (f32x4){0.f, 0.f, 0.f, 0.f};
  }
  float mA = NEG_BIG, lA = 0.f, mB = NEG_BIG, lB = 0.f;

  const int krow = t >> 2;
  const int kc   = (t & 3) << 1;
  const int kr7  = krow & 7;
  const int vu   = t >> 7;            // which half this thread stages for V
  const int tl   = t & 127;
  const int vkq  = (tl & 15) << 2;
  const int vd8  = (tl >> 4) << 3;
  const int vg   = vkq >> 3;
  const int vh   = (vkq >> 2) & 1;

  const int npairA = (qbA >> 1) + 1;
  const int npairB = (qbB >> 1) + 1;

  for (int pr = 0; pr < npairB; ++pr) {
    const int kt2 = pr * 2;
    __syncthreads();
    // ---- stage K, both halves ----
#pragma unroll
    for (int u = 0; u < 2; ++u) {
      const unsigned short* kp =
          K + base + (size_t)((kt2 + u) * 64 + krow) * DK + (kc << 3);
      uint4 k0 = *(const uint4*)kp;
      uint4 k1 = *(const uint4*)(kp + 8);
      *(uint4*)(Ks[u] + krow * 64 + ((kc ^ kr7) << 3))       = k0;
      *(uint4*)(Ks[u] + krow * 64 + (((kc + 1) ^ kr7) << 3)) = k1;
    }
    // ---- stage V transposed, half vu per thread ----
    {
      const unsigned short* vp =
          V + base + (size_t)((kt2 + vu) * 64 + vkq) * DK + vd8;
      uint4 u0 = *(const uint4*)(vp);
      uint4 u1 = *(const uint4*)(vp + DK);
      uint4 u2 = *(const uint4*)(vp + 2 * DK);
      uint4 u3 = *(const uint4*)(vp + 3 * DK);
      const unsigned short* a0 = (const unsigned short*)&u0;
      const unsigned short* a1 = (const unsigned short*)&u1;
      const unsigned short* a2 = (const unsigned short*)&u2;
      const unsigned short* a3 = (const unsigned short*)&u3;
#pragma unroll
      for (int j = 0; j < 8; ++j) {
        const int dk = vd8 + j;
        const int slot = vg ^ (dk & 7);
        ushort4 pk;
        pk.x = a0[j]; pk.y = a1[j]; pk.z = a2[j]; pk.w = a3[j];
        *(ushort4*)(Vt[vu] + dk * 64 + (slot << 3) + (vh << 2)) = pk;
      }
    }
    __syncthreads();

    // ---- long tile always; short tile while in range (uniform branches) ----
    attn_step(Ks[0], Ks[1], Vt[0], Vt[1], qfB0, qfB1, i16, q4, w,
              q0B, kt2, pr == npairB - 1, mB, lB, oB);
    if (pr < npairA)
      attn_step(Ks[0], Ks[1], Vt[0], Vt[1], qfA0, qfA1, i16, q4, w,
                q0A, kt2, pr == npairA - 1, mA, lA, oA);
  }

  // ---- epilogues ----
  const int b = bh >> 4, h = bh & 15;
#pragma unroll
  for (int r = 0; r < 4; ++r) {
    const float lrA = __shfl(lA, (q4 << 2) + r, 64);
    const float lrB = __shfl(lB, (q4 << 2) + r, 64);
    const float invA = 1.0f / lrA;
    const float invB = 1.0f / lrB;
    const int sA = q0A + w * 16 + (q4 << 2) + r;
    const int sB = q0B + w * 16 + (q4 << 2) + r;
#pragma unroll
    for (int nt = 0; nt < 4; ++nt) {
      const int dk = nt * 16 + i16;
      O[((size_t)(b * SEQ + sA)) * D_MODEL + h * DK + dk] = f2bf(oA[nt][r] * invA);
      O[((size_t)(b * SEQ + sB)) * D_MODEL + h * DK + dk] = f2bf(oB[nt][r] * invB);
    }
  }
}

// ---------------------------------------------------------------------------
// Kernel 3: output projection -> fp32, float4 packed stores. grid (32, 16).
// ---------------------------------------------------------------------------
__global__ __launch_bounds__(256) void oproj_kernel(
    const unsigned short* __restrict__ ain, const unsigned short* __restrict__ wo,
    float* __restrict__ out) {
  __shared__ __align__(16) unsigned short As[128 * 64];
  __shared__ __align__(16) unsigned short Bs[64 * 64];
  f32x4 acc[2][4];
  const int m0 = blockIdx.x * 128;
  const int n0 = blockIdx.y * 64;
  gemm_bt_64T(ain, wo, m0, n0, As, Bs, acc);

  const int t = threadIdx.x, lane = t & 63, w = t >> 6;
  const int wm = (w >> 1) * 64, wn = (w & 1) * 32;
  const int i16 = lane & 15, q4 = lane >> 4;
#pragma unroll
  for (int ft = 0; ft < 2; ++ft) {
    const int nb0 = n0 + wn + ft * 16 + (q4 << 2);
#pragma unroll
    for (int tt = 0; tt < 4; ++tt) {
      const int m = m0 + wm + tt * 16 + i16;
      float4 v;
      v.x = acc[ft][tt][0]; v.y = acc[ft][tt][1];
      v.z = acc[ft][tt][2]; v.w = acc[ft][tt][3];
      *(float4*)(out + (size_t)m * D_MODEL + nb0) = v;
    }
  }
}

// ---------------------------------------------------------------------------
extern "C" void kernel_launch(void* const* d_in, const int* in_sizes, int n_in,
                              void* d_out, int out_size, void* d_ws, size_t ws_size,
                              hipStream_t stream) {
  const void* x    = d_in[0];
  const void* wqkv = d_in[2];
  const void* wo   = d_in[3];
  float* out = (float*)d_out;

  const size_t NTOK  = (size_t)NBATCH * SEQ * D_MODEL;  // 4,194,304 elements
  const size_t NWQKV = (size_t)3 * D_MODEL * D_MODEL;   // 3,145,728
  const size_t NWO   = (size_t)D_MODEL * D_MODEL;       // 1,048,576

  unsigned int*   flag = (unsigned int*)d_ws;
  unsigned short* base = (unsigned short*)((char*)d_ws + 16);
  unsigned short* Qw = base;                 // NTOK
  unsigned short* Kw = Qw + NTOK;            // NTOK
  unsigned short* Vw = Kw + NTOK;            // NTOK
  unsigned short* Aw = Vw + NTOK;            // NTOK (aliases xb; xb dead before attn writes)
  unsigned short* xb = Aw;                   // canonical bf16 x
  unsigned short* wq = Aw + NTOK;            // NWQKV (wo reuses after qkv done)
  unsigned short* wb = wq;                   // canonical bf16 wo

  dim3 blk(256);
  hipLaunchKernelGGL(sniff_kernel, dim3(1), blk, 0, stream,
                     (const unsigned short*)x, flag);
  hipLaunchKernelGGL(cvt_kernel, dim3((unsigned)(NTOK / 8 + 255) / 256), blk, 0, stream,
                     x, xb, (int)(NTOK / 8), flag);
  hipLaunchKernelGGL(cvt_kernel, dim3((unsigned)(NWQKV / 8 + 255) / 256), blk, 0, stream,
                     wqkv, wq, (int)(NWQKV / 8), flag);

  dim3 g1(32, 48);  // M/128 x 3072/64
  hipLaunchKernelGGL(qkv_rope_kernel, g1, blk, 0, stream, xb, wq, Qw, Kw, Vw);

  dim3 g2(SEQ / 128, NBATCH * NHEADS);  // paired q-tiles: uniform work
  hipLaunchKernelGGL(attn_mfma_kernel, g2, blk, 0, stream, Qw, Kw, Vw, Aw);

  hipLaunchKernelGGL(cvt_kernel, dim3((unsigned)(NWO / 8 + 255) / 256), blk, 0, stream,
                     wo, wb, (int)(NWO / 8), flag);

  dim3 g3(32, 16);  // M/128 x 1024/64
  hipLaunchKernelGGL(oproj_kernel, g3, blk, 0, stream, Aw, wb, out);
}